// Round 14
// baseline (231.209 us; speedup 1.0000x reference)
//
#include <hip/hip_runtime.h>
#include <hip/hip_bf16.h>

#define B_SZ 32
#define N_SZ 2048
#define H_SZ 1024

typedef float f32x4 __attribute__((ext_vector_type(4)));
typedef short bf16x8 __attribute__((ext_vector_type(8)));

static __device__ __forceinline__ unsigned short f2bf(float f) {
    union { float f; unsigned u; } x; x.f = f;
    unsigned r = x.u + 0x7FFF + ((x.u >> 16) & 1);
    return (unsigned short)(r >> 16);
}

// fast tanh: (e^{2x}-1)/(e^{2x}+1), clamped so e never overflows
static __device__ __forceinline__ float fast_tanh(float x) {
    x = fminf(fmaxf(x, -15.f), 15.f);
    float e = __expf(2.f * x);
    return (e - 1.f) / (e + 1.f);
}

// ---------------- kernel 1: pack Wv f32 -> bf16 in wave-fragment order ----------------
__global__ __launch_bounds__(256) void pack_wv_kernel(const float* __restrict__ wv,
                                                      short* __restrict__ out) {
    int o8 = blockIdx.x * 256 + threadIdx.x;
    int lane = o8 & 63;
    int t    = (o8 >> 6) & 3;
    int k    = (o8 >> 8) & 31;
    int w    = (o8 >> 13) & 15;
    int g  = w * 64 + 16 * t + (lane & 15);
    int h0 = k * 32 + (lane >> 4) * 8;
    const float* src = wv + (size_t)g * 1024 + h0;
    float4 v0 = *(const float4*)(src);
    float4 v1 = *(const float4*)(src + 4);
    short4 s0, s1;
    s0.x = (short)f2bf(v0.x); s0.y = (short)f2bf(v0.y);
    s0.z = (short)f2bf(v0.z); s0.w = (short)f2bf(v0.w);
    s1.x = (short)f2bf(v1.x); s1.y = (short)f2bf(v1.y);
    s1.z = (short)f2bf(v1.z); s1.w = (short)f2bf(v1.w);
    *(short4*)(out + (size_t)o8 * 8)     = s0;
    *(short4*)(out + (size_t)o8 * 8 + 4) = s1;
}

// ---------------- kernel 2: q_hid = query @ Wq.T + bias ----------------
__global__ __launch_bounds__(256) void qhid_kernel(const float* __restrict__ query,
                                                   const float* __restrict__ Wq,
                                                   const float* __restrict__ bias,
                                                   float* __restrict__ qh) {
    int gb = blockIdx.x * 4;
    __shared__ float wsm[4][1024];
    int t = threadIdx.x;
    for (int i = t; i < 4096; i += 256)
        wsm[i >> 10][i & 1023] = Wq[(size_t)gb * 1024 + i];
    __syncthreads();
    int gi = t >> 6;
    int lane = t & 63;
    int b = lane >> 1;
    int half = lane & 1;
    const float4* q = (const float4*)(query + b * 1024 + half * 512);
    const float4* w = (const float4*)(&wsm[gi][half * 512]);
    float acc = 0.f;
#pragma unroll 8
    for (int h = 0; h < 128; ++h) {
        float4 qv = q[h]; float4 wv = w[h];
        acc += qv.x * wv.x + qv.y * wv.y + qv.z * wv.z + qv.w * wv.w;
    }
    acc += __shfl_xor(acc, 1);
    if (half == 0) qh[b * 1024 + gb + gi] = acc + bias[gb + gi];
}

// ---------------- kernel 3: fused score GEMM + tanh + Wm dot ----------------
// 512 threads (8 waves, 2 waves/SIMD, 256-reg budget); one 64-row panel per
// block; full K=1024 in LDS. Wave owns 128 g (2 packed slots, acc 4x8).
// Depth-1 parity prefetch of A (aE/aO, ds_reads for k+1 issue under k's MFMAs)
// and reload-after-use B; sched_group_barrier forces per-wave interleave
// (4 MFMA : 1 VMEM : DS spread) so every wave keeps matrix+LDS+L2 pipes fed.
__global__ __launch_bounds__(512, 2) void fused_score_kernel(
    const float* __restrict__ value, const float* __restrict__ cov,
    const short* __restrict__ wv_pk, const float* __restrict__ qh,
    const float* __restrict__ Wc, const float* __restrict__ Wm,
    float* __restrict__ e_out)
{
    extern __shared__ char smem[];
    float* e_sm = (float*)(smem + 64 * 1024 * 2);

    const int p   = blockIdx.x;
    const int b   = p >> 5;
    const int n0  = (p & 31) * 64;
    const int tid = threadIdx.x;

    if (tid < 64) e_sm[tid] = 0.f;

    // ---- stage value[b, n0..n0+64, :] as bf16 into swizzled LDS ----
    const float* src = value + ((size_t)(b * N_SZ + n0)) * H_SZ;
#pragma unroll 4
    for (int it = 0; it < 32; ++it) {
        int idx = (it * 512 + tid) * 4;
        float4 v = *(const float4*)(src + idx);
        int row = idx >> 10;
        int col = idx & 1023;
        unsigned byteoff = (unsigned)(row * 2048 + col * 2) ^ (unsigned)((row & 7) << 4);
        short4 s;
        s.x = (short)f2bf(v.x); s.y = (short)f2bf(v.y);
        s.z = (short)f2bf(v.z); s.w = (short)f2bf(v.w);
        *(short4*)(smem + byteoff) = s;
    }
    __syncthreads();

    const int wave = tid >> 6;                   // 0..7
    const int lane = tid & 63;
    const int lrow = lane & 15;
    const int lgrp = lane >> 4;
    const unsigned xorm = (unsigned)((lrow & 7) << 4);
    const unsigned base_e = ((unsigned)(lrow * 2048 + lgrp * 16)) ^ xorm; // k even
    const unsigned base_o = base_e ^ 64u;        // bit6 of pre-XOR addr is 0 -> +64 == ^64

    // uniform B base for this wave's two packed slots (helps SGPR folding)
    const int wslot = __builtin_amdgcn_readfirstlane(wave * 2);
    const short* su = wv_pk + (size_t)wslot * 65536;
    const int lo = lane * 8;                     // per-lane element offset

// A-fragment ds loads (4 x b128), chunkless full-K layout, byte offsets
#define LDA(dst, BASE, OFF)                                                     \
    dst[0] = *(const bf16x8*)(smem + (BASE) + (OFF));                           \
    dst[1] = *(const bf16x8*)(smem + (BASE) + (OFF) + 32768u);                  \
    dst[2] = *(const bf16x8*)(smem + (BASE) + (OFF) + 65536u);                  \
    dst[3] = *(const bf16x8*)(smem + (BASE) + (OFF) + 98304u);
// B loads: dst[0..3] slot0, dst[4..7] slot1; KOFF in shorts (= k*2048)
#define LDB2(dst, KOFF)                                                         \
    dst[0] = *(const bf16x8*)(su + (KOFF) + lo);                                \
    dst[1] = *(const bf16x8*)(su + (KOFF) + 512 + lo);                          \
    dst[2] = *(const bf16x8*)(su + (KOFF) + 1024 + lo);                         \
    dst[3] = *(const bf16x8*)(su + (KOFF) + 1536 + lo);                         \
    dst[4] = *(const bf16x8*)(su + 65536 + (KOFF) + lo);                        \
    dst[5] = *(const bf16x8*)(su + 65536 + (KOFF) + 512 + lo);                  \
    dst[6] = *(const bf16x8*)(su + 65536 + (KOFF) + 1024 + lo);                 \
    dst[7] = *(const bf16x8*)(su + 65536 + (KOFF) + 1536 + lo);
// 32 MFMA, t-outer so bE[t]'s last use is early -> its reload interleaves
#define MM32(A, B)                                                              \
    _Pragma("unroll")                                                           \
    for (int t = 0; t < 8; ++t) {                                               \
        _Pragma("unroll")                                                       \
        for (int r = 0; r < 4; ++r)                                             \
            acc[r][t] = __builtin_amdgcn_mfma_f32_16x16x32_bf16(                \
                A[r], B[t], acc[r][t], 0, 0, 0);                                \
    }
// schedule prescription: 8 x {4 MFMA, 1 VMEM_READ}, DS_READ spread every other
#define SGB_SUBSTEP                                                             \
    _Pragma("unroll")                                                           \
    for (int t = 0; t < 8; ++t) {                                               \
        __builtin_amdgcn_sched_group_barrier(0x008, 4, 0);                      \
        __builtin_amdgcn_sched_group_barrier(0x020, 1, 0);                      \
        if (t & 1) __builtin_amdgcn_sched_group_barrier(0x100, 1, 0);           \
    }

    f32x4 acc[4][8];
#pragma unroll
    for (int r = 0; r < 4; ++r)
#pragma unroll
        for (int t = 0; t < 8; ++t) acc[r][t] = (f32x4){0.f, 0.f, 0.f, 0.f};

    bf16x8 aE[4], aO[4], bE[8], bO[8];
    LDA(aE, base_e, 0u)          // A k=0
    LDB2(bE, 0)                  // B k=0
    LDB2(bO, 2048)               // B k=1

    int kOffE = 4096;            // next even-k B source (k=2), shorts
    int kOffO = 6144;            // next odd-k B source (k=3)
    unsigned aOffO = 0;          // aO load offset: base_o + kp*128 (k=2kp+1)
    unsigned aOffE = 128;        // aE load offset: base_e + (kp+1)*128 (k=2kp+2)

#pragma unroll 1
    for (int kp = 0; kp < 16; ++kp) {
        // ---- even sub-step: k=2kp ----
        MM32(aE, bE)
        LDA(aO, base_o, aOffO)   // prefetch A for k=2kp+1
        LDB2(bE, kOffE)          // reload B for k=2kp+2 (kp=15: unused overread)
        SGB_SUBSTEP
        aOffO += 128; kOffE += 4096;

        // ---- odd sub-step: k=2kp+1 ----
        MM32(aO, bO)
        LDA(aE, base_e, aOffE)   // prefetch A for k=2kp+2 (kp=15: unused)
        LDB2(bO, kOffO)          // reload B for k=2kp+3 (kp=15: unused)
        SGB_SUBSTEP
        aOffE += 128; kOffO += 4096;
    }
#undef LDA
#undef LDB2
#undef MM32
#undef SGB_SUBSTEP

    // epilogue: a = acc + qh + cov*Wc ; e_part += tanh(a)*Wm
    float cv[4][4];
#pragma unroll
    for (int r = 0; r < 4; ++r)
#pragma unroll
        for (int i = 0; i < 4; ++i)
            cv[r][i] = cov[b * N_SZ + n0 + 16 * r + lgrp * 4 + i];

    float s_part[4][4];
#pragma unroll
    for (int r = 0; r < 4; ++r)
#pragma unroll
        for (int i = 0; i < 4; ++i) s_part[r][i] = 0.f;

#pragma unroll
    for (int t = 0; t < 8; ++t) {
        int g = wave * 128 + (t >> 2) * 64 + (t & 3) * 16 + lrow;
        float qv = qh[b * 1024 + g];
        float wc = Wc[g];
        float wm = Wm[g];
#pragma unroll
        for (int r = 0; r < 4; ++r)
#pragma unroll
            for (int i = 0; i < 4; ++i) {
                float aval = acc[r][t][i] + qv + cv[r][i] * wc;
                s_part[r][i] += fast_tanh(aval) * wm;
            }
    }

    // reduce across the 16 lanes sharing a row, then accumulate into LDS
#pragma unroll
    for (int r = 0; r < 4; ++r)
#pragma unroll
        for (int i = 0; i < 4; ++i) {
            float s = s_part[r][i];
            s += __shfl_xor(s, 1);
            s += __shfl_xor(s, 2);
            s += __shfl_xor(s, 4);
            s += __shfl_xor(s, 8);
            if (lrow == 0) atomicAdd(&e_sm[16 * r + lgrp * 4 + i], s);
        }
    __syncthreads();
    if (tid < 64) e_out[b * N_SZ + n0 + tid] = e_sm[tid];
}

// ---------------- kernel 4: mask + softmax over n ----------------
__global__ __launch_bounds__(256) void softmax_kernel(const float* __restrict__ e,
                                                      const int* __restrict__ mask,
                                                      const float* __restrict__ bm,
                                                      float* __restrict__ attn_out) {
    int b = blockIdx.x;
    int t = threadIdx.x;
    int wave = t >> 6, lane = t & 63;
    float bmv = bm[0];
    float vals[8];
    float mx = -1e30f;
#pragma unroll
    for (int j = 0; j < 8; ++j) {
        int n = t + 256 * j;
        float ev = e[b * N_SZ + n] + bmv;
        if (mask[b * N_SZ + n] <= 0) ev = -1e9f;
        vals[j] = ev;
        mx = fmaxf(mx, ev);
    }
#pragma unroll
    for (int m = 1; m < 64; m <<= 1) mx = fmaxf(mx, __shfl_xor(mx, m));
    __shared__ float redmax[4], redsum[4];
    if (lane == 0) redmax[wave] = mx;
    __syncthreads();
    mx = fmaxf(fmaxf(redmax[0], redmax[1]), fmaxf(redmax[2], redmax[3]));
    float sum = 0.f;
#pragma unroll
    for (int j = 0; j < 8; ++j) {
        vals[j] = expf(vals[j] - mx);
        sum += vals[j];
    }
#pragma unroll
    for (int m = 1; m < 64; m <<= 1) sum += __shfl_xor(sum, m);
    if (lane == 0) redsum[wave] = sum;
    __syncthreads();
    sum = redsum[0] + redsum[1] + redsum[2] + redsum[3];
    float inv = 1.f / sum;
#pragma unroll
    for (int j = 0; j < 8; ++j)
        attn_out[b * N_SZ + t + 256 * j] = vals[j] * inv;
}

// ---------------- kernel 5: partial weighted value sum (16 chunks/batch) ----------------
__global__ __launch_bounds__(256) void wsum_partial_kernel(const float* __restrict__ attn,
                                                           const float* __restrict__ value,
                                                           float* __restrict__ partial) {
    int b = blockIdx.x >> 4;
    int c = blockIdx.x & 15;
    int t = threadIdx.x;
    float4 acc = {0.f, 0.f, 0.f, 0.f};
    const float* vbase = value + (size_t)(b * N_SZ + c * 128) * H_SZ;
    const float* abase = attn + b * N_SZ + c * 128;
    for (int n = 0; n < 128; ++n) {
        float a = abase[n];
        if (a != 0.f) {
            float4 v = *(const float4*)(vbase + (size_t)n * H_SZ + t * 4);
            acc.x += a * v.x; acc.y += a * v.y;
            acc.z += a * v.z; acc.w += a * v.w;
        }
    }
    *(float4*)(partial + (size_t)blockIdx.x * H_SZ + t * 4) = acc;
}

// ---------------- kernel 6: reduce partials -> output ----------------
__global__ __launch_bounds__(256) void wsum_reduce_kernel(const float* __restrict__ partial,
                                                          float* __restrict__ out) {
    int i = blockIdx.x * 256 + threadIdx.x;   // 32768 total
    int b = i >> 10;
    int h = i & 1023;
    float s = 0.f;
#pragma unroll
    for (int c = 0; c < 16; ++c) s += partial[(size_t)(b * 16 + c) * H_SZ + h];
    out[i] = s;
}

extern "C" void kernel_launch(void* const* d_in, const int* in_sizes, int n_in,
                              void* d_out, int out_size, void* d_ws, size_t ws_size,
                              hipStream_t stream) {
    const float* query = (const float*)d_in[0];
    const float* value = (const float*)d_in[1];
    const int*   mask  = (const int*)  d_in[2];
    const float* cov   = (const float*)d_in[3];
    const float* Wq    = (const float*)d_in[4];
    const float* Wv    = (const float*)d_in[5];
    const float* Wc    = (const float*)d_in[6];
    const float* bias  = (const float*)d_in[7];
    const float* Wm    = (const float*)d_in[8];
    const float* bm    = (const float*)d_in[9];

    float* out      = (float*)d_out;            // [32*1024] output
    float* attn_out = out + B_SZ * H_SZ;        // [32*2048] attn

    char* ws = (char*)d_ws;
    short* wv_pk   = (short*)ws;                                       // 2 MB
    float* qh      = (float*)(ws + 2 * 1024 * 1024);                   // 128 KB
    float* e_buf   = (float*)(ws + 2 * 1024 * 1024 + 128 * 1024);      // 256 KB
    float* partial = (float*)(ws + 2 * 1024 * 1024 + 384 * 1024);      // 2 MB

    pack_wv_kernel<<<512, 256, 0, stream>>>(Wv, wv_pk);
    qhid_kernel<<<256, 256, 0, stream>>>(query, Wq, bias, qh);

    size_t smem = 64 * 1024 * 2 + 256;
    fused_score_kernel<<<1024, 512, smem, stream>>>(value, cov, wv_pk, qh, Wc, Wm, e_buf);

    softmax_kernel<<<B_SZ, 256, 0, stream>>>(e_buf, mask, bm, attn_out);
    wsum_partial_kernel<<<B_SZ * 16, 256, 0, stream>>>(attn_out, value, partial);
    wsum_reduce_kernel<<<128, 256, 0, stream>>>(partial, out);
}

// Round 15
// 228.182 us; speedup vs baseline: 1.0133x; 1.0133x over previous
//
#include <hip/hip_runtime.h>
#include <hip/hip_bf16.h>

#define B_SZ 32
#define N_SZ 2048
#define H_SZ 1024

typedef float f32x4 __attribute__((ext_vector_type(4)));
typedef short bf16x8 __attribute__((ext_vector_type(8)));

static __device__ __forceinline__ unsigned short f2bf(float f) {
    union { float f; unsigned u; } x; x.f = f;
    unsigned r = x.u + 0x7FFF + ((x.u >> 16) & 1);
    return (unsigned short)(r >> 16);
}

// fast tanh: (e^{2x}-1)/(e^{2x}+1), clamped so e never overflows
static __device__ __forceinline__ float fast_tanh(float x) {
    x = fminf(fmaxf(x, -15.f), 15.f);
    float e = __expf(2.f * x);
    return (e - 1.f) / (e + 1.f);
}

// ---------------- kernel 1: pack Wv f32 -> bf16 in wave-fragment order ----------------
// packed element index: ((((w*32 + k)*4 + t)*64) + lane)*8 + j
//   maps to Wv[g][h], g = w*64 + 16t + (lane&15), h = k*32 + (lane>>4)*8 + j
__global__ __launch_bounds__(256) void pack_wv_kernel(const float* __restrict__ wv,
                                                      short* __restrict__ out) {
    int o8 = blockIdx.x * 256 + threadIdx.x;      // 131072 threads, 8 elems each
    int lane = o8 & 63;
    int t    = (o8 >> 6) & 3;
    int k    = (o8 >> 8) & 31;
    int w    = (o8 >> 13) & 15;
    int g  = w * 64 + 16 * t + (lane & 15);
    int h0 = k * 32 + (lane >> 4) * 8;
    const float* src = wv + (size_t)g * 1024 + h0;
    float4 v0 = *(const float4*)(src);
    float4 v1 = *(const float4*)(src + 4);
    short4 s0, s1;
    s0.x = (short)f2bf(v0.x); s0.y = (short)f2bf(v0.y);
    s0.z = (short)f2bf(v0.z); s0.w = (short)f2bf(v0.w);
    s1.x = (short)f2bf(v1.x); s1.y = (short)f2bf(v1.y);
    s1.z = (short)f2bf(v1.z); s1.w = (short)f2bf(v1.w);
    *(short4*)(out + (size_t)o8 * 8)     = s0;
    *(short4*)(out + (size_t)o8 * 8 + 4) = s1;
}

// ---------------- kernel 2: q_hid = query @ Wq.T + bias ----------------
__global__ __launch_bounds__(256) void qhid_kernel(const float* __restrict__ query,
                                                   const float* __restrict__ Wq,
                                                   const float* __restrict__ bias,
                                                   float* __restrict__ qh) {
    int gb = blockIdx.x * 4;
    __shared__ float wsm[4][1024];
    int t = threadIdx.x;
    for (int i = t; i < 4096; i += 256)
        wsm[i >> 10][i & 1023] = Wq[(size_t)gb * 1024 + i];
    __syncthreads();
    int gi = t >> 6;
    int lane = t & 63;
    int b = lane >> 1;
    int half = lane & 1;
    const float4* q = (const float4*)(query + b * 1024 + half * 512);
    const float4* w = (const float4*)(&wsm[gi][half * 512]);
    float acc = 0.f;
#pragma unroll 8
    for (int h = 0; h < 128; ++h) {
        float4 qv = q[h]; float4 wv = w[h];
        acc += qv.x * wv.x + qv.y * wv.y + qv.z * wv.z + qv.w * wv.w;
    }
    acc += __shfl_xor(acc, 1);
    if (half == 0) qh[b * 1024 + gb + gi] = acc + bias[gb + gi];
}

// ---------------- kernel 3: fused score GEMM + tanh + Wm dot ----------------
// 512 threads (8 waves); block = one 64-row panel x one 512-g half.
// SIBLING PAIRING FIX (vs r8): p = ((wgid>>4)<<3)|(wgid&7), ghalf = (wgid>>3)&1
// -> sibling blocks (same panel, both g-halves) are 8 apart in blockIdx ->
// same XCD under round-robin -> panel's 2nd HBM read is an L2 hit (r12
// verified FETCH stays ~165MB with this mapping; r8's adjacent-bid pairing
// cost +130MB HBM and cancelled the 2-blocks/CU staging overlap).
// LDS = 64KB A-tile (K chunked 2x512, single buffer) -> 2 blocks/CU:
// one block's serial staging hides under the other's barrier-free k-loop.
__global__ __launch_bounds__(512, 4) void fused_score_kernel(
    const float* __restrict__ value, const float* __restrict__ cov,
    const short* __restrict__ wv_pk, const float* __restrict__ qh,
    const float* __restrict__ Wc, const float* __restrict__ Wm,
    float* __restrict__ e_part)
{
    extern __shared__ char smem[];                 // 64KB A-chunk + e_sm
    float* e_sm = (float*)(smem + 65536);

    const int wgid  = blockIdx.x;
    const int p     = ((wgid >> 4) << 3) | (wgid & 7);   // panel 0..1023
    const int ghalf = (wgid >> 3) & 1;                   // which 512-g half
    const int b     = p >> 5;
    const int n0    = (p & 31) * 64;
    const int tid   = threadIdx.x;

    if (tid < 64) e_sm[tid] = 0.f;

    // staging role: lanes 0-7 share a row (128B contiguous global segments)
    const int srow  = tid >> 3;                    // 0..63
    const int scol8 = tid & 7;                     // 0..7 (8 f32 each)
    const float* gsrc = value + ((size_t)(b * N_SZ + n0) + srow) * H_SZ + scol8 * 8;
    const unsigned wswz = (unsigned)((srow & 7) << 4);
    const unsigned wbase = (unsigned)(srow * 1024 + scol8 * 16);

#define STAGE_CHUNK(CB)                                                        \
    {                                                                          \
        _Pragma("unroll")                                                      \
        for (int it = 0; it < 8; ++it) {                                       \
            float4 q0 = *(const float4*)(gsrc + (CB) + it * 64);               \
            float4 q1 = *(const float4*)(gsrc + (CB) + it * 64 + 4);           \
            bf16x8 w;                                                          \
            w[0] = (short)f2bf(q0.x); w[1] = (short)f2bf(q0.y);                \
            w[2] = (short)f2bf(q0.z); w[3] = (short)f2bf(q0.w);                \
            w[4] = (short)f2bf(q1.x); w[5] = (short)f2bf(q1.y);                \
            w[6] = (short)f2bf(q1.z); w[7] = (short)f2bf(q1.w);                \
            *(bf16x8*)(smem + ((wbase + (unsigned)(it * 128)) ^ wswz)) = w;    \
        }                                                                      \
    }

    // ---- stage chunk 0 (cols 0-511) ----
    STAGE_CHUNK(0)
    __syncthreads();

    const int wave = tid >> 6;
    const int lane = tid & 63;
    const int lrow = lane & 15;
    const int lgrp = lane >> 4;
    const unsigned xorm = (unsigned)((lrow & 7) << 4);
    // chunk-local swizzled bases (row stride 1024B), ks-parity split
    const unsigned base_e = ((unsigned)(lrow * 1024 + lgrp * 16)) ^ xorm;      // ks even
    const unsigned base_o = ((unsigned)(lrow * 1024 + 64 + lgrp * 16)) ^ xorm; // ks odd

    float cv[4][4];
#pragma unroll
    for (int r = 0; r < 4; ++r)
#pragma unroll
        for (int i = 0; i < 4; ++i)
            cv[r][i] = cov[b * N_SZ + n0 + 16 * r + lgrp * 4 + i];

    const int wslot = ghalf * 8 + wave;            // 64-g block index 0..15
    const short* bbase = wv_pk + (size_t)wslot * 65536 + lane * 8;

    f32x4 acc[4][4];
#pragma unroll
    for (int r = 0; r < 4; ++r)
#pragma unroll
        for (int t = 0; t < 4; ++t) acc[r][t] = (f32x4){0.f, 0.f, 0.f, 0.f};

    // B ping buffer (flat-k ping/pong, continuous across the two chunks)
    bf16x8 bc[4];
#pragma unroll
    for (int t = 0; t < 4; ++t)
        bc[t] = *(const bf16x8*)(bbase + t * 512);

#pragma unroll 1
    for (int c = 0; c < 2; ++c) {
        if (c == 1) {
            __syncthreads();                        // k-loop c0 done reading
            STAGE_CHUNK(512)
            __syncthreads();
        }
#pragma unroll 2
        for (int ks = 0; ks < 16; ++ks) {
            const int kf = c * 16 + ks;
            // prefetch next flat-k B fragments (wrap at end: harmless reload)
            bf16x8 bn[4];
            const int kn = (kf + 1) & 31;
#pragma unroll
            for (int t = 0; t < 4; ++t)
                bn[t] = *(const bf16x8*)(bbase + kn * 2048 + t * 512);

            bf16x8 afr[4];
            const unsigned P = ((ks & 1) ? base_o : base_e) + (unsigned)((ks >> 1) * 128);
#pragma unroll
            for (int r = 0; r < 4; ++r)
                afr[r] = *(const bf16x8*)(smem + P + (unsigned)(r * 16384));
#pragma unroll
            for (int r = 0; r < 4; ++r)
#pragma unroll
                for (int t = 0; t < 4; ++t)
                    acc[r][t] = __builtin_amdgcn_mfma_f32_16x16x32_bf16(
                        afr[r], bc[t], acc[r][t], 0, 0, 0);
#pragma unroll
            for (int t = 0; t < 4; ++t) bc[t] = bn[t];
        }
    }
#undef STAGE_CHUNK

    // epilogue: a = acc + qh + cov*Wc ; e_part += tanh(a)*Wm
    const int gbase = ghalf * 512 + wave * 64;
    float s_part[4][4];
#pragma unroll
    for (int r = 0; r < 4; ++r)
#pragma unroll
        for (int i = 0; i < 4; ++i) s_part[r][i] = 0.f;

#pragma unroll
    for (int t = 0; t < 4; ++t) {
        int g = gbase + 16 * t + lrow;
        float qv = qh[b * 1024 + g];
        float wc = Wc[g];
        float wm = Wm[g];
#pragma unroll
        for (int r = 0; r < 4; ++r)
#pragma unroll
            for (int i = 0; i < 4; ++i) {
                float aval = acc[r][t][i] + qv + cv[r][i] * wc;
                s_part[r][i] += fast_tanh(aval) * wm;
            }
    }

    // reduce across the 16 lanes sharing a row, then accumulate into LDS
#pragma unroll
    for (int r = 0; r < 4; ++r)
#pragma unroll
        for (int i = 0; i < 4; ++i) {
            float s = s_part[r][i];
            s += __shfl_xor(s, 1);
            s += __shfl_xor(s, 2);
            s += __shfl_xor(s, 4);
            s += __shfl_xor(s, 8);
            if (lrow == 0) atomicAdd(&e_sm[16 * r + lgrp * 4 + i], s);
        }
    __syncthreads();
    if (tid < 64)
        e_part[((size_t)ghalf * B_SZ + b) * N_SZ + n0 + tid] = e_sm[tid];
}

// ---------------- kernel 4: mask + softmax over n (sums the two e-halves) ----------------
__global__ __launch_bounds__(256) void softmax_kernel(const float* __restrict__ e_part,
                                                      const int* __restrict__ mask,
                                                      const float* __restrict__ bm,
                                                      float* __restrict__ attn_out) {
    int b = blockIdx.x;
    int t = threadIdx.x;
    int wave = t >> 6, lane = t & 63;
    float bmv = bm[0];
    float vals[8];
    float mx = -1e30f;
#pragma unroll
    for (int j = 0; j < 8; ++j) {
        int n = t + 256 * j;
        float ev = e_part[(size_t)b * N_SZ + n]
                 + e_part[((size_t)B_SZ + b) * N_SZ + n] + bmv;
        if (mask[b * N_SZ + n] <= 0) ev = -1e9f;
        vals[j] = ev;
        mx = fmaxf(mx, ev);
    }
#pragma unroll
    for (int m = 1; m < 64; m <<= 1) mx = fmaxf(mx, __shfl_xor(mx, m));
    __shared__ float redmax[4], redsum[4];
    if (lane == 0) redmax[wave] = mx;
    __syncthreads();
    mx = fmaxf(fmaxf(redmax[0], redmax[1]), fmaxf(redmax[2], redmax[3]));
    float sum = 0.f;
#pragma unroll
    for (int j = 0; j < 8; ++j) {
        vals[j] = expf(vals[j] - mx);
        sum += vals[j];
    }
#pragma unroll
    for (int m = 1; m < 64; m <<= 1) sum += __shfl_xor(sum, m);
    if (lane == 0) redsum[wave] = sum;
    __syncthreads();
    sum = redsum[0] + redsum[1] + redsum[2] + redsum[3];
    float inv = 1.f / sum;
#pragma unroll
    for (int j = 0; j < 8; ++j)
        attn_out[b * N_SZ + t + 256 * j] = vals[j] * inv;
}

// ---------------- kernel 5: partial weighted value sum (16 chunks/batch) ----------------
__global__ __launch_bounds__(256) void wsum_partial_kernel(const float* __restrict__ attn,
                                                           const float* __restrict__ value,
                                                           float* __restrict__ partial) {
    int b = blockIdx.x >> 4;
    int c = blockIdx.x & 15;
    int t = threadIdx.x;
    float4 acc = {0.f, 0.f, 0.f, 0.f};
    const float* vbase = value + (size_t)(b * N_SZ + c * 128) * H_SZ;
    const float* abase = attn + b * N_SZ + c * 128;
    for (int n = 0; n < 128; ++n) {
        float a = abase[n];
        if (a != 0.f) {
            float4 v = *(const float4*)(vbase + (size_t)n * H_SZ + t * 4);
            acc.x += a * v.x; acc.y += a * v.y;
            acc.z += a * v.z; acc.w += a * v.w;
        }
    }
    *(float4*)(partial + (size_t)blockIdx.x * H_SZ + t * 4) = acc;
}

// ---------------- kernel 6: reduce partials -> output ----------------
__global__ __launch_bounds__(256) void wsum_reduce_kernel(const float* __restrict__ partial,
                                                          float* __restrict__ out) {
    int i = blockIdx.x * 256 + threadIdx.x;   // 32768 total
    int b = i >> 10;
    int h = i & 1023;
    float s = 0.f;
#pragma unroll
    for (int c = 0; c < 16; ++c) s += partial[(size_t)(b * 16 + c) * H_SZ + h];
    out[i] = s;
}

extern "C" void kernel_launch(void* const* d_in, const int* in_sizes, int n_in,
                              void* d_out, int out_size, void* d_ws, size_t ws_size,
                              hipStream_t stream) {
    const float* query = (const float*)d_in[0];
    const float* value = (const float*)d_in[1];
    const int*   mask  = (const int*)  d_in[2];
    const float* cov   = (const float*)d_in[3];
    const float* Wq    = (const float*)d_in[4];
    const float* Wv    = (const float*)d_in[5];
    const float* Wc    = (const float*)d_in[6];
    const float* bias  = (const float*)d_in[7];
    const float* Wm    = (const float*)d_in[8];
    const float* bm    = (const float*)d_in[9];

    float* out      = (float*)d_out;            // [32*1024] output
    float* attn_out = out + B_SZ * H_SZ;        // [32*2048] attn

    char* ws = (char*)d_ws;
    short* wv_pk   = (short*)ws;                                       // 2 MB
    float* qh      = (float*)(ws + 2 * 1024 * 1024);                   // 128 KB
    float* e_part  = (float*)(ws + 2 * 1024 * 1024 + 128 * 1024);      // 512 KB (2 halves)
    float* partial = (float*)(ws + 2 * 1024 * 1024 + 640 * 1024);      // 2 MB

    pack_wv_kernel<<<512, 256, 0, stream>>>(Wv, wv_pk);
    qhid_kernel<<<256, 256, 0, stream>>>(query, Wq, bias, qh);

    size_t smem = 65536 + 256;
    fused_score_kernel<<<2048, 512, smem, stream>>>(value, cov, wv_pk, qh, Wc, Wm, e_part);

    softmax_kernel<<<B_SZ, 256, 0, stream>>>(e_part, mask, bm, attn_out);
    wsum_partial_kernel<<<B_SZ * 16, 256, 0, stream>>>(attn_out, value, partial);
    wsum_reduce_kernel<<<128, 256, 0, stream>>>(partial, out);
}